// Round 24
// baseline (403.661 us; speedup 1.0000x reference)
//
#include <hip/hip_runtime.h>
#include <hip/hip_bf16.h>

#define NN_NODES 20000
#define NE_EDGES 500000
#define KTOT 48
#define BTSTRIDE 40

typedef __bf16 bf16x8 __attribute__((ext_vector_type(8)));
typedef float f32x4 __attribute__((ext_vector_type(4)));

__device__ inline unsigned short bf16_rne(float x) {
    unsigned int u = __float_as_uint(x);
    u = (u + 0x7fffu + ((u >> 16) & 1u)) >> 16;
    return (unsigned short)u;
}

// ---------------------------------------------------------------------------
// Zero helper
// ---------------------------------------------------------------------------
__global__ void zero_kernel(int* __restrict__ p, int n) {
    int i = blockIdx.x * 256 + threadIdx.x;
    if (i < n) p[i] = 0;
}

// ---------------------------------------------------------------------------
// CSR build: count + scan (fill is fused into edge_prep)
// ---------------------------------------------------------------------------
__global__ void count_kernel(const int* __restrict__ ei, int* __restrict__ counts) {
    int e = blockIdx.x * 256 + threadIdx.x;
    if (e < NE_EDGES) atomicAdd(&counts[ei[NE_EDGES + e]], 1);
}

__global__ void scan_kernel(const int* __restrict__ counts, int* __restrict__ row_start) {
    __shared__ int part[256];
    const int CH = (NN_NODES + 255) / 256;
    int t = threadIdx.x;
    int begin = t * CH;
    int end = begin + CH;
    if (end > NN_NODES) end = NN_NODES;
    int sum = 0;
    for (int i = begin; i < end && i < NN_NODES; ++i) sum += counts[i];
    part[t] = sum;
    __syncthreads();
    for (int off = 1; off < 256; off <<= 1) {
        int v = (t >= off) ? part[t - off] : 0;
        __syncthreads();
        part[t] += v;
        __syncthreads();
    }
    int run = (t == 0) ? 0 : part[t - 1];
    for (int i = begin; i < end && i < NN_NODES; ++i) {
        row_start[i] = run;
        run += counts[i];
    }
    if (t == 255) row_start[NN_NODES] = part[255];
}

// ---------------------------------------------------------------------------
// Degree-sorted permutation (counting sort, 128 bins): blocks of the fused
// layer kernels get degree-homogeneous node sets -> barrier straggler waste
// (max over 16 Poisson draws vs mean) collapses to ~7%.
// ---------------------------------------------------------------------------
__global__ void hist_kernel(const int* __restrict__ counts, int* __restrict__ hist) {
    int n = blockIdx.x * 256 + threadIdx.x;
    if (n < NN_NODES) atomicAdd(&hist[min(counts[n], 127)], 1);
}

__global__ void scan128_kernel(const int* __restrict__ hist, int* __restrict__ offs) {
    __shared__ int tmp[128];
    int t = threadIdx.x;
    tmp[t] = hist[t];
    __syncthreads();
    for (int off = 1; off < 128; off <<= 1) {
        int v = (t >= off) ? tmp[t - off] : 0;
        __syncthreads();
        tmp[t] += v;
        __syncthreads();
    }
    offs[t] = tmp[t] - hist[t];   // exclusive prefix
}

__global__ void scatter_perm_kernel(const int* __restrict__ counts, int* __restrict__ offs,
                                    int* __restrict__ perm) {
    int n = blockIdx.x * 256 + threadIdx.x;
    if (n < NN_NODES) {
        int d = min(counts[n], 127);
        int r = atomicAdd(&offs[d], 1);
        perm[r] = n;
    }
}

// ---------------------------------------------------------------------------
// Edge prep + fill fused (CSR slot order). Basis stored directly as BF16.
// All 8 kidx of an edge pairwise DISTINCT (clamped corners redirected).
// ---------------------------------------------------------------------------
__global__ void edge_prep_sorted(const float* __restrict__ pseudo, const int* __restrict__ ei,
                                 const int* __restrict__ row_start, int* __restrict__ cursor,
                                 int* __restrict__ srcs,
                                 unsigned short* __restrict__ bas8bf,
                                 unsigned char* __restrict__ kidb) {
    int e = blockIdx.x * 256 + threadIdx.x;
    if (e >= NE_EDGES) return;
    const int ksa[3] = {3, 8, 2};
    float frac[3];
    int id_lo[3], id_hi[3];
#pragma unroll
    for (int d = 0; d < 3; ++d) {
        float u = pseudo[e * 3 + d] * (1.0f / 4.5f);
        u = fminf(fmaxf(u, 0.0f), 1.0f);
        float pos = u * (float)(ksa[d] - 1);
        float fl = floorf(pos);
        int lo = (int)fl;
        frac[d] = pos - fl;
        id_lo[d] = lo;
        id_hi[d] = (lo + 1 <= ksa[d] - 1) ? lo + 1 : lo - 1;
    }
    int d0 = ei[NE_EDGES + e];
    int p = atomicAdd(&cursor[d0], 1);
    int j = row_start[d0] + p;
    srcs[j] = ei[e];
#pragma unroll
    for (int s = 0; s < 8; ++s) {
        float w = 1.0f;
        int k = 0;
        const int strides[3] = {16, 2, 1};
#pragma unroll
        for (int d = 0; d < 3; ++d) {
            int bit = (s >> d) & 1;
            k += (bit ? id_hi[d] : id_lo[d]) * strides[d];
            w *= bit ? frac[d] : (1.0f - frac[d]);
        }
        bas8bf[(size_t)j * 8 + s] = bf16_rne(w);
        kidb[(size_t)j * 8 + s] = (unsigned char)k;
    }
}

// ---------------------------------------------------------------------------
// Layer 1 FUSED (c_in = 1): wave per node; emits bf16 h1. Basis read as bf16.
// ---------------------------------------------------------------------------
__global__ __launch_bounds__(256) void layer1_fused_kernel(
    const int* __restrict__ srcs, const unsigned short* __restrict__ bas8bf,
    const unsigned char* __restrict__ kidb, const int* __restrict__ row_start,
    const float* __restrict__ x, const float* __restrict__ W1,
    const float* __restrict__ root1, const float* __restrict__ b1,
    unsigned short* __restrict__ h1bf) {
    __shared__ float w1s[KTOT * 32];
    __shared__ float scopy[4][8 * 49];
    int tid = threadIdx.x;
    for (int l = tid; l < KTOT * 32; l += 256) w1s[l] = W1[l];
    int w = tid >> 6, lane = tid & 63;
    int n = blockIdx.x * 4 + w;
    bool act = n < NN_NODES;
    float* sc = &scopy[w][0];
    for (int l = lane; l < 8 * 49; l += 64) sc[l] = 0.0f;
    if (act) {
        int beg = row_start[n], end = row_start[n + 1];
        int es = lane >> 3;
        for (int jb = beg; jb < end; jb += 8) {
            int j = jb + es;
            if (j < end) {
                float b = __uint_as_float((unsigned)bas8bf[(size_t)jb * 8 + lane] << 16);
                int k = kidb[(size_t)jb * 8 + lane];
                float xv = x[srcs[j]];
                sc[es * 49 + k] += b * xv;
            }
        }
        if (lane < KTOT) {
            float a = 0.0f;
#pragma unroll
            for (int e = 0; e < 8; ++e) a += sc[e * 49 + lane];
            sc[lane] = a;
        }
    }
    __syncthreads();
    if (act && lane < 32) {
        float s = b1[lane] + x[n] * root1[lane];
#pragma unroll 8
        for (int k = 0; k < KTOT; ++k) s = fmaf(sc[k], w1s[k * 32 + lane], s);
        h1bf[n * 32 + lane] = bf16_rne(fmaxf(s, 0.0f));
    }
}

// ---------------------------------------------------------------------------
// Pack W' = [W(KK rows); root(CP rows)] into MFMA B-fragment order.
// ---------------------------------------------------------------------------
__global__ void pack_w_kernel(const float* __restrict__ W, const float* __restrict__ root,
                              int KK, int NN, int total, unsigned short* __restrict__ Wp) {
    int tid = blockIdx.x * 256 + threadIdx.x;
    if (tid >= total) return;
    int nct = NN >> 4;
    int l = tid & 63;
    int c = (tid >> 6) % nct;
    int t = tid / (64 * nct);
    int n = c * 16 + (l & 15);
    int kbase = t * 32 + ((l >> 4) << 3);
    unsigned short vals[8];
#pragma unroll
    for (int jj = 0; jj < 8; ++jj) {
        int k = kbase + jj;
        float v = (k < KK) ? W[(size_t)k * NN + n] : root[(size_t)(k - KK) * NN + n];
        vals[jj] = bf16_rne(v);
    }
    *(uint4*)&Wp[(size_t)tid * 8] = *(uint4*)vals;
}

// ---------------------------------------------------------------------------
// FUSED layer 2: 1024 threads (16 waves), 16 nodes (degree-sorted via perm),
// 1 node/wave phase 1. Arows: k-row stride 36, node stride 1816.
// Phase 2: 4 column tiles x 4-way K-split; Cst overlay on dead Bt region.
// LDS = 119,552 B -> 1 block/CU, 16 waves.
// ---------------------------------------------------------------------------
#define NSTR2 1816
__global__ __launch_bounds__(1024) void fused_l2_kernel(
    const int* __restrict__ srcs, const unsigned short* __restrict__ bas8bf,
    const unsigned char* __restrict__ kidb, const int* __restrict__ row_start,
    const int* __restrict__ perm,
    const unsigned short* __restrict__ h1bf, const unsigned short* __restrict__ Wp2,
    const float* __restrict__ b2, unsigned short* __restrict__ h2bf) {
    __shared__ unsigned short Arows[16 * NSTR2];
    __shared__ unsigned short BtAll[16][KTOT * BTSTRIDE];
    float* Cst = (float*)&BtAll[0][0];
    int w = threadIdx.x >> 6, lane = threadIdx.x & 63;
    int q = lane >> 4, l15 = lane & 15;
    unsigned short* Bt = &BtAll[w][0];

    // ---- phase 1: one node per wave ----
    {
        int n = perm[blockIdx.x * 16 + w];
        int beg = row_start[n], end = row_start[n + 1];
        int cnt = end - beg;
        f32x4 acc[3][2] = {};
        for (int c0 = 0; c0 < cnt; c0 += 32) {
            uint4 z = make_uint4(0, 0, 0, 0);
            for (int l = lane; l < (KTOT * BTSTRIDE) / 8; l += 64) ((uint4*)Bt)[l] = z;
#pragma unroll
            for (int it = 0; it < 4; ++it) {
                int idx = it * 64 + lane;
                int jj = idx >> 3, s = idx & 7;
                int j = c0 + jj;
                if (j < cnt) {
                    unsigned short b = bas8bf[(size_t)(beg + j) * 8 + s];
                    int k = kidb[(size_t)(beg + j) * 8 + s];
                    Bt[k * BTSTRIDE + jj] = b;
                }
            }
            int srcv[8];
#pragma unroll
            for (int j = 0; j < 8; ++j) {
                int jc = c0 + q * 8 + j;
                jc = (jc < cnt) ? jc : (cnt - 1);
                srcv[j] = srcs[beg + jc];
            }
            bf16x8 afr[3];
#pragma unroll
            for (int mt = 0; mt < 3; ++mt) {
                uint4 raw = *(const uint4*)&Bt[(mt * 16 + l15) * BTSTRIDE + q * 8];
                afr[mt] = __builtin_bit_cast(bf16x8, raw);
            }
#pragma unroll
            for (int nt = 0; nt < 2; ++nt) {
                unsigned int bw[4];
#pragma unroll
                for (int jp = 0; jp < 4; ++jp) {
                    unsigned int lo = h1bf[(size_t)srcv[2 * jp] * 32 + nt * 16 + l15];
                    unsigned int hi = h1bf[(size_t)srcv[2 * jp + 1] * 32 + nt * 16 + l15];
                    bw[jp] = lo | (hi << 16);
                }
                uint4 braw = make_uint4(bw[0], bw[1], bw[2], bw[3]);
                bf16x8 bfr = __builtin_bit_cast(bf16x8, braw);
#pragma unroll
                for (int mt = 0; mt < 3; ++mt)
                    acc[mt][nt] = __builtin_amdgcn_mfma_f32_16x16x32_bf16(
                        afr[mt], bfr, acc[mt][nt], 0, 0, 0);
            }
        }
        unsigned short* arow = &Arows[w * NSTR2];
#pragma unroll
        for (int mt = 0; mt < 3; ++mt)
#pragma unroll
            for (int nt = 0; nt < 2; ++nt)
#pragma unroll
                for (int r = 0; r < 4; ++r)
                    arow[(mt * 16 + q * 4 + r) * 36 + nt * 16 + l15] =
                        bf16_rne(acc[mt][nt][r]);
        if (lane < 32) arow[48 * 36 + lane] = h1bf[(size_t)n * 32 + lane];
    }
    __syncthreads();

    // ---- phase 2: wave w -> column tile (w&3), K-quarter (w>>2) ----
    {
        int tile = w & 3;
        int kq = w >> 2;
        int t0 = (kq * 49) / 4, t1 = ((kq + 1) * 49) / 4;
        f32x4 cacc = {};
        const uint4* wpq = (const uint4*)Wp2;
        uint4 nb = wpq[((size_t)t0 * 4 + tile) * 64 + lane];
        for (int t = t0; t < t1; ++t) {
            uint4 cb = nb;
            int tn = (t + 1 < t1) ? t + 1 : t;
            nb = wpq[((size_t)tn * 4 + tile) * 64 + lane];
            bf16x8 af = __builtin_bit_cast(
                bf16x8, *(const uint4*)&Arows[l15 * NSTR2 + t * 36 + (q << 3)]);
            bf16x8 bfr = __builtin_bit_cast(bf16x8, cb);
            cacc = __builtin_amdgcn_mfma_f32_16x16x32_bf16(af, bfr, cacc, 0, 0, 0);
        }
        float* cpart = Cst + kq * (16 * 66);
#pragma unroll
        for (int r = 0; r < 4; ++r)
            cpart[(q * 4 + r) * 66 + tile * 16 + l15] = cacc[r];
    }
    __syncthreads();

    // ---- fused epilogue: reduce quarters + bias + relu -> bf16 h2 ----
    {
        int row = threadIdx.x >> 6;        // 0..15
        int col = threadIdx.x & 63;        // 0..63
        int idx = row * 66 + col;
        float v = Cst[idx] + Cst[16 * 66 + idx] + Cst[32 * 66 + idx] + Cst[48 * 66 + idx];
        v = fmaxf(v + b2[col], 0.0f);
        int n = perm[blockIdx.x * 16 + row];
        h2bf[(size_t)n * 64 + col] = bf16_rne(v);
    }
}

// ---------------------------------------------------------------------------
// FUSED layer 3: 1024 threads (16 waves), 16 nodes (degree-sorted via perm),
// 1 node/wave phase 1; Arows plain layout arow[kk*64+ch], ASTR=3160.
// Phase 2: 8 column tiles x 2-way K-split. Fused log_softmax epilogue.
// LDS = 162,560 B -> 1 block/CU, 16 waves.
// ---------------------------------------------------------------------------
#define ASTR 3160
__global__ __launch_bounds__(1024) void fused_l3_kernel(
    const int* __restrict__ srcs, const unsigned short* __restrict__ bas8bf,
    const unsigned char* __restrict__ kidb, const int* __restrict__ row_start,
    const int* __restrict__ perm,
    const unsigned short* __restrict__ h2bf, const unsigned short* __restrict__ Wp3,
    const float* __restrict__ b3, float* __restrict__ out) {
    __shared__ unsigned short Arows[16 * ASTR];
    __shared__ unsigned short BtAll[16][KTOT * BTSTRIDE];
    float* Cst = (float*)&BtAll[0][0];
    int w = threadIdx.x >> 6, lane = threadIdx.x & 63;
    int q = lane >> 4, l15 = lane & 15;
    unsigned short* Bt = &BtAll[w][0];

    // ---- phase 1: one node per wave ----
    {
        int n = perm[blockIdx.x * 16 + w];
        int beg = row_start[n], end = row_start[n + 1];
        int cnt = end - beg;
        f32x4 acc[3][4] = {};
        for (int c0 = 0; c0 < cnt; c0 += 32) {
            uint4 z = make_uint4(0, 0, 0, 0);
            for (int l = lane; l < (KTOT * BTSTRIDE) / 8; l += 64) ((uint4*)Bt)[l] = z;
#pragma unroll
            for (int it = 0; it < 4; ++it) {
                int idx = it * 64 + lane;
                int jj = idx >> 3, s = idx & 7;
                int j = c0 + jj;
                if (j < cnt) {
                    unsigned short b = bas8bf[(size_t)(beg + j) * 8 + s];
                    int k = kidb[(size_t)(beg + j) * 8 + s];
                    Bt[k * BTSTRIDE + jj] = b;
                }
            }
            int srcv[8];
#pragma unroll
            for (int j = 0; j < 8; ++j) {
                int jc = c0 + q * 8 + j;
                jc = (jc < cnt) ? jc : (cnt - 1);
                srcv[j] = srcs[beg + jc];
            }
            bf16x8 afr[3];
#pragma unroll
            for (int mt = 0; mt < 3; ++mt) {
                uint4 raw = *(const uint4*)&Bt[(mt * 16 + l15) * BTSTRIDE + q * 8];
                afr[mt] = __builtin_bit_cast(bf16x8, raw);
            }
#pragma unroll
            for (int nt = 0; nt < 4; ++nt) {
                unsigned int bw[4];
#pragma unroll
                for (int jp = 0; jp < 4; ++jp) {
                    unsigned int lo = h2bf[(size_t)srcv[2 * jp] * 64 + nt * 16 + l15];
                    unsigned int hi = h2bf[(size_t)srcv[2 * jp + 1] * 64 + nt * 16 + l15];
                    bw[jp] = lo | (hi << 16);
                }
                uint4 braw = make_uint4(bw[0], bw[1], bw[2], bw[3]);
                bf16x8 bfr = __builtin_bit_cast(bf16x8, braw);
#pragma unroll
                for (int mt = 0; mt < 3; ++mt)
                    acc[mt][nt] = __builtin_amdgcn_mfma_f32_16x16x32_bf16(
                        afr[mt], bfr, acc[mt][nt], 0, 0, 0);
            }
        }
        unsigned short* arow = &Arows[w * ASTR];
#pragma unroll
        for (int mt = 0; mt < 3; ++mt)
#pragma unroll
            for (int nt = 0; nt < 4; ++nt)
#pragma unroll
                for (int r = 0; r < 4; ++r)
                    arow[(mt * 16 + q * 4 + r) * 64 + nt * 16 + l15] =
                        bf16_rne(acc[mt][nt][r]);
        arow[3072 + lane] = h2bf[(size_t)n * 64 + lane];
    }
    __syncthreads();

    // ---- phase 2: wave w -> column tile (w&7), K-half (w>>3) ----
    {
        int tile = w & 7;
        int half = w >> 3;
        int t0 = half * 49, t1 = t0 + 49;
        f32x4 cacc = {};
        const uint4* wpq = (const uint4*)Wp3;
        uint4 nb = wpq[((size_t)t0 * 8 + tile) * 64 + lane];
        for (int t = t0; t < t1; ++t) {
            uint4 cb = nb;
            int tn = (t + 1 < t1) ? t + 1 : t;
            nb = wpq[((size_t)tn * 8 + tile) * 64 + lane];
            bf16x8 af = __builtin_bit_cast(
                bf16x8, *(const uint4*)&Arows[l15 * ASTR + t * 32 + (q << 3)]);
            bf16x8 bfr = __builtin_bit_cast(bf16x8, cb);
            cacc = __builtin_amdgcn_mfma_f32_16x16x32_bf16(af, bfr, cacc, 0, 0, 0);
        }
        float* chalf = Cst + half * (16 * 130);
#pragma unroll
        for (int r = 0; r < 4; ++r)
            chalf[(q * 4 + r) * 130 + tile * 16 + l15] = cacc[r];
    }
    __syncthreads();

    // ---- fused epilogue: reduce halves + bias + relu + log_softmax ----
    if (threadIdx.x < 256) {
        int row = threadIdx.x >> 4;
        int cb0 = threadIdx.x & 15;
        float v[8];
        float mx = -1e30f;
#pragma unroll
        for (int c = 0; c < 8; ++c) {
            int idx = row * 130 + cb0 + c * 16;
            float s = Cst[idx] + Cst[16 * 130 + idx] + b3[cb0 + c * 16];
            s = fmaxf(s, 0.0f);
            v[c] = s;
            mx = fmaxf(mx, s);
        }
#pragma unroll
        for (int off = 8; off > 0; off >>= 1) mx = fmaxf(mx, __shfl_xor(mx, off));
        float se = 0.0f;
#pragma unroll
        for (int c = 0; c < 8; ++c) se += expf(v[c] - mx);
#pragma unroll
        for (int off = 8; off > 0; off >>= 1) se += __shfl_xor(se, off);
        float lse = mx + logf(se);
        int n = perm[blockIdx.x * 16 + row];
#pragma unroll
        for (int c = 0; c < 8; ++c)
            out[(size_t)n * 128 + cb0 + c * 16] = v[c] - lse;
    }
}

// ---------------------------------------------------------------------------
// Launch
// ---------------------------------------------------------------------------
extern "C" void kernel_launch(void* const* d_in, const int* in_sizes, int n_in,
                              void* d_out, int out_size, void* d_ws, size_t ws_size,
                              hipStream_t stream) {
    const float* x = (const float*)d_in[0];
    const int* ei = (const int*)d_in[1];
    const float* pseudo = (const float*)d_in[2];
    const float* W1 = (const float*)d_in[3];
    const float* root1 = (const float*)d_in[4];
    const float* b1 = (const float*)d_in[5];
    const float* W2 = (const float*)d_in[6];
    const float* root2 = (const float*)d_in[7];
    const float* b2 = (const float*)d_in[8];
    const float* W3 = (const float*)d_in[9];
    const float* root3 = (const float*)d_in[10];
    const float* b3 = (const float*)d_in[11];
    float* out = (float*)d_out;
    char* ws = (char*)d_ws;

    const int N = NN_NODES, E = NE_EDGES;
    const int Kp2 = 49 * 32;   // 1568
    const int Kp3 = 49 * 64;   // 3136
    size_t off = 0;
    auto carve = [&](size_t bytes) {
        size_t p = off;
        off += (bytes + 255) & ~(size_t)255;
        return p;
    };
    int* counts = (int*)(ws + carve((size_t)N * 4 * 2));
    int* cursor = counts + N;
    int* row_start = (int*)(ws + carve((size_t)(N + 1) * 4));
    int* hist = (int*)(ws + carve(256 * 4));        // hist[128] + offs[128]
    int* offs = hist + 128;
    int* perm = (int*)(ws + carve((size_t)N * 4));
    int* srcs = (int*)(ws + carve((size_t)E * 4));
    unsigned short* bas8bf = (unsigned short*)(ws + carve((size_t)E * 8 * 2));
    unsigned char* kidb = (unsigned char*)(ws + carve((size_t)E * 8));
    unsigned short* h1bf = (unsigned short*)(ws + carve((size_t)N * 32 * 2));
    unsigned short* h2bf = (unsigned short*)(ws + carve((size_t)N * 64 * 2));
    unsigned short* Wp2 = (unsigned short*)(ws + carve((size_t)Kp2 * 64 * 2));
    unsigned short* Wp3 = (unsigned short*)(ws + carve((size_t)Kp3 * 128 * 2));

    int egrid = (E + 255) / 256;
    int ngrid = (N + 255) / 256;

    // CSR + degree-sorted permutation + sorted edge metadata
    zero_kernel<<<(2 * N + 255) / 256, 256, 0, stream>>>(counts, 2 * N);
    zero_kernel<<<1, 256, 0, stream>>>(hist, 256);
    count_kernel<<<egrid, 256, 0, stream>>>(ei, counts);
    scan_kernel<<<1, 256, 0, stream>>>(counts, row_start);
    hist_kernel<<<ngrid, 256, 0, stream>>>(counts, hist);
    scan128_kernel<<<1, 128, 0, stream>>>(hist, offs);
    scatter_perm_kernel<<<ngrid, 256, 0, stream>>>(counts, offs, perm);
    edge_prep_sorted<<<egrid, 256, 0, stream>>>(pseudo, ei, row_start, cursor,
                                                srcs, bas8bf, kidb);

    // pack weights (bf16 MFMA B-fragment order)
    int tot2 = (Kp2 / 32) * (64 / 16) * 64;
    int tot3 = (Kp3 / 32) * (128 / 16) * 64;
    pack_w_kernel<<<(tot2 + 255) / 256, 256, 0, stream>>>(W2, root2, KTOT * 32, 64, tot2, Wp2);
    pack_w_kernel<<<(tot3 + 255) / 256, 256, 0, stream>>>(W3, root3, KTOT * 64, 128, tot3, Wp3);

    // layer 1 (fused accumulate + dense + relu) -> bf16 h1
    layer1_fused_kernel<<<(N + 3) / 4, 256, 0, stream>>>(srcs, bas8bf, kidb, row_start, x,
                                                         W1, root1, b1, h1bf);

    // layer 2: fused kernel over degree-sorted nodes -> bf16 h2
    fused_l2_kernel<<<N / 16, 1024, 0, stream>>>(srcs, bas8bf, kidb, row_start, perm,
                                                 h1bf, Wp2, b2, h2bf);

    // layer 3: fused kernel over degree-sorted nodes -> out
    fused_l3_kernel<<<N / 16, 1024, 0, stream>>>(srcs, bas8bf, kidb, row_start, perm,
                                                 h2bf, Wp3, b3, out);
}

// Round 25
// 289.024 us; speedup vs baseline: 1.3966x; 1.3966x over previous
//
#include <hip/hip_runtime.h>
#include <hip/hip_bf16.h>

#define NN_NODES 20000
#define NE_EDGES 500000
#define KTOT 48
#define BTSTRIDE 40

typedef __bf16 bf16x8 __attribute__((ext_vector_type(8)));
typedef float f32x4 __attribute__((ext_vector_type(4)));

__device__ inline unsigned short bf16_rne(float x) {
    unsigned int u = __float_as_uint(x);
    u = (u + 0x7fffu + ((u >> 16) & 1u)) >> 16;
    return (unsigned short)u;
}

// ---------------------------------------------------------------------------
// Zero helper
// ---------------------------------------------------------------------------
__global__ void zero_kernel(int* __restrict__ p, int n) {
    int i = blockIdx.x * 256 + threadIdx.x;
    if (i < n) p[i] = 0;
}

// ---------------------------------------------------------------------------
// CSR build: count + scan (fill is fused into edge_prep)
// ---------------------------------------------------------------------------
__global__ void count_kernel(const int* __restrict__ ei, int* __restrict__ counts) {
    int e = blockIdx.x * 256 + threadIdx.x;
    if (e < NE_EDGES) atomicAdd(&counts[ei[NE_EDGES + e]], 1);
}

__global__ void scan_kernel(const int* __restrict__ counts, int* __restrict__ row_start) {
    __shared__ int part[256];
    const int CH = (NN_NODES + 255) / 256;
    int t = threadIdx.x;
    int begin = t * CH;
    int end = begin + CH;
    if (end > NN_NODES) end = NN_NODES;
    int sum = 0;
    for (int i = begin; i < end && i < NN_NODES; ++i) sum += counts[i];
    part[t] = sum;
    __syncthreads();
    for (int off = 1; off < 256; off <<= 1) {
        int v = (t >= off) ? part[t - off] : 0;
        __syncthreads();
        part[t] += v;
        __syncthreads();
    }
    int run = (t == 0) ? 0 : part[t - 1];
    for (int i = begin; i < end && i < NN_NODES; ++i) {
        row_start[i] = run;
        run += counts[i];
    }
    if (t == 255) row_start[NN_NODES] = part[255];
}

// ---------------------------------------------------------------------------
// Edge prep + fill fused (CSR slot order). Basis stored directly as BF16.
// All 8 kidx of an edge pairwise DISTINCT (clamped corners redirected).
// ---------------------------------------------------------------------------
__global__ void edge_prep_sorted(const float* __restrict__ pseudo, const int* __restrict__ ei,
                                 const int* __restrict__ row_start, int* __restrict__ cursor,
                                 int* __restrict__ srcs,
                                 unsigned short* __restrict__ bas8bf,
                                 unsigned char* __restrict__ kidb) {
    int e = blockIdx.x * 256 + threadIdx.x;
    if (e >= NE_EDGES) return;
    const int ksa[3] = {3, 8, 2};
    float frac[3];
    int id_lo[3], id_hi[3];
#pragma unroll
    for (int d = 0; d < 3; ++d) {
        float u = pseudo[e * 3 + d] * (1.0f / 4.5f);
        u = fminf(fmaxf(u, 0.0f), 1.0f);
        float pos = u * (float)(ksa[d] - 1);
        float fl = floorf(pos);
        int lo = (int)fl;
        frac[d] = pos - fl;
        id_lo[d] = lo;
        id_hi[d] = (lo + 1 <= ksa[d] - 1) ? lo + 1 : lo - 1;
    }
    int d0 = ei[NE_EDGES + e];
    int p = atomicAdd(&cursor[d0], 1);
    int j = row_start[d0] + p;
    srcs[j] = ei[e];
#pragma unroll
    for (int s = 0; s < 8; ++s) {
        float w = 1.0f;
        int k = 0;
        const int strides[3] = {16, 2, 1};
#pragma unroll
        for (int d = 0; d < 3; ++d) {
            int bit = (s >> d) & 1;
            k += (bit ? id_hi[d] : id_lo[d]) * strides[d];
            w *= bit ? frac[d] : (1.0f - frac[d]);
        }
        bas8bf[(size_t)j * 8 + s] = bf16_rne(w);
        kidb[(size_t)j * 8 + s] = (unsigned char)k;
    }
}

// ---------------------------------------------------------------------------
// Layer 1 FUSED (c_in = 1): wave per node; emits bf16 h1. Basis read as bf16.
// ---------------------------------------------------------------------------
__global__ __launch_bounds__(256) void layer1_fused_kernel(
    const int* __restrict__ srcs, const unsigned short* __restrict__ bas8bf,
    const unsigned char* __restrict__ kidb, const int* __restrict__ row_start,
    const float* __restrict__ x, const float* __restrict__ W1,
    const float* __restrict__ root1, const float* __restrict__ b1,
    unsigned short* __restrict__ h1bf) {
    __shared__ float w1s[KTOT * 32];
    __shared__ float scopy[4][8 * 49];
    int tid = threadIdx.x;
    for (int l = tid; l < KTOT * 32; l += 256) w1s[l] = W1[l];
    int w = tid >> 6, lane = tid & 63;
    int n = blockIdx.x * 4 + w;
    bool act = n < NN_NODES;
    float* sc = &scopy[w][0];
    for (int l = lane; l < 8 * 49; l += 64) sc[l] = 0.0f;
    if (act) {
        int beg = row_start[n], end = row_start[n + 1];
        int es = lane >> 3;
        for (int jb = beg; jb < end; jb += 8) {
            int j = jb + es;
            if (j < end) {
                float b = __uint_as_float((unsigned)bas8bf[(size_t)jb * 8 + lane] << 16);
                int k = kidb[(size_t)jb * 8 + lane];
                float xv = x[srcs[j]];
                sc[es * 49 + k] += b * xv;
            }
        }
        if (lane < KTOT) {
            float a = 0.0f;
#pragma unroll
            for (int e = 0; e < 8; ++e) a += sc[e * 49 + lane];
            sc[lane] = a;
        }
    }
    __syncthreads();
    if (act && lane < 32) {
        float s = b1[lane] + x[n] * root1[lane];
#pragma unroll 8
        for (int k = 0; k < KTOT; ++k) s = fmaf(sc[k], w1s[k * 32 + lane], s);
        h1bf[n * 32 + lane] = bf16_rne(fmaxf(s, 0.0f));
    }
}

// ---------------------------------------------------------------------------
// Pack W' = [W(KK rows); root(CP rows)] into MFMA B-fragment order.
// ---------------------------------------------------------------------------
__global__ void pack_w_kernel(const float* __restrict__ W, const float* __restrict__ root,
                              int KK, int NN, int total, unsigned short* __restrict__ Wp) {
    int tid = blockIdx.x * 256 + threadIdx.x;
    if (tid >= total) return;
    int nct = NN >> 4;
    int l = tid & 63;
    int c = (tid >> 6) % nct;
    int t = tid / (64 * nct);
    int n = c * 16 + (l & 15);
    int kbase = t * 32 + ((l >> 4) << 3);
    unsigned short vals[8];
#pragma unroll
    for (int jj = 0; jj < 8; ++jj) {
        int k = kbase + jj;
        float v = (k < KK) ? W[(size_t)k * NN + n] : root[(size_t)(k - KK) * NN + n];
        vals[jj] = bf16_rne(v);
    }
    *(uint4*)&Wp[(size_t)tid * 8] = *(uint4*)vals;
}

// ---------------------------------------------------------------------------
// FUSED layer 2: 1024 threads (16 waves), 16 nodes, 1 node/wave phase 1.
// Arows layout: k-row stride 36 ushorts (pad 4), node stride 1816 (=24 mod 64)
// -> conflict-minimal writeout AND phase-2 A-reads.
// Phase 2: 4 column tiles x 4-way K-split; Cst overlay on dead Bt region.
// LDS = 16*1816*2 + 16*1920*2 = 119,552 B -> 1 block/CU, 16 waves.
// ---------------------------------------------------------------------------
#define NSTR2 1816
__global__ __launch_bounds__(1024) void fused_l2_kernel(
    const int* __restrict__ srcs, const unsigned short* __restrict__ bas8bf,
    const unsigned char* __restrict__ kidb, const int* __restrict__ row_start,
    const unsigned short* __restrict__ h1bf, const unsigned short* __restrict__ Wp2,
    const float* __restrict__ b2, unsigned short* __restrict__ h2bf) {
    __shared__ unsigned short Arows[16 * NSTR2];          // 58,112 B
    __shared__ unsigned short BtAll[16][KTOT * BTSTRIDE]; // 61,440 B (Cst overlay)
    float* Cst = (float*)&BtAll[0][0];                    // 4 x 16 x 66 fp32
    int w = threadIdx.x >> 6, lane = threadIdx.x & 63;
    int q = lane >> 4, l15 = lane & 15;
    unsigned short* Bt = &BtAll[w][0];

    // ---- phase 1: one node per wave (proven mfma_acc<32> body) ----
    {
        int n = blockIdx.x * 16 + w;
        int beg = row_start[n], end = row_start[n + 1];
        int cnt = end - beg;
        f32x4 acc[3][2] = {};
        for (int c0 = 0; c0 < cnt; c0 += 32) {
            uint4 z = make_uint4(0, 0, 0, 0);
            for (int l = lane; l < (KTOT * BTSTRIDE) / 8; l += 64) ((uint4*)Bt)[l] = z;
#pragma unroll
            for (int it = 0; it < 4; ++it) {
                int idx = it * 64 + lane;
                int jj = idx >> 3, s = idx & 7;
                int j = c0 + jj;
                if (j < cnt) {
                    unsigned short b = bas8bf[(size_t)(beg + j) * 8 + s];
                    int k = kidb[(size_t)(beg + j) * 8 + s];
                    Bt[k * BTSTRIDE + jj] = b;
                }
            }
            int srcv[8];
#pragma unroll
            for (int j = 0; j < 8; ++j) {
                int jc = c0 + q * 8 + j;
                jc = (jc < cnt) ? jc : (cnt - 1);
                srcv[j] = srcs[beg + jc];
            }
            bf16x8 afr[3];
#pragma unroll
            for (int mt = 0; mt < 3; ++mt) {
                uint4 raw = *(const uint4*)&Bt[(mt * 16 + l15) * BTSTRIDE + q * 8];
                afr[mt] = __builtin_bit_cast(bf16x8, raw);
            }
#pragma unroll
            for (int nt = 0; nt < 2; ++nt) {
                unsigned int bw[4];
#pragma unroll
                for (int jp = 0; jp < 4; ++jp) {
                    unsigned int lo = h1bf[(size_t)srcv[2 * jp] * 32 + nt * 16 + l15];
                    unsigned int hi = h1bf[(size_t)srcv[2 * jp + 1] * 32 + nt * 16 + l15];
                    bw[jp] = lo | (hi << 16);
                }
                uint4 braw = make_uint4(bw[0], bw[1], bw[2], bw[3]);
                bf16x8 bfr = __builtin_bit_cast(bf16x8, braw);
#pragma unroll
                for (int mt = 0; mt < 3; ++mt)
                    acc[mt][nt] = __builtin_amdgcn_mfma_f32_16x16x32_bf16(
                        afr[mt], bfr, acc[mt][nt], 0, 0, 0);
            }
        }
        unsigned short* arow = &Arows[w * NSTR2];
#pragma unroll
        for (int mt = 0; mt < 3; ++mt)
#pragma unroll
            for (int nt = 0; nt < 2; ++nt)
#pragma unroll
                for (int r = 0; r < 4; ++r)
                    arow[(mt * 16 + q * 4 + r) * 36 + nt * 16 + l15] =
                        bf16_rne(acc[mt][nt][r]);
        if (lane < 32) arow[48 * 36 + lane] = h1bf[(size_t)n * 32 + lane];
    }
    __syncthreads();

    // ---- phase 2: wave w -> column tile (w&3), K-quarter (w>>2) ----
    {
        int tile = w & 3;
        int kq = w >> 2;
        int t0 = (kq * 49) / 4, t1 = ((kq + 1) * 49) / 4;
        f32x4 cacc = {};
        const uint4* wpq = (const uint4*)Wp2;
        uint4 nb = wpq[((size_t)t0 * 4 + tile) * 64 + lane];
        for (int t = t0; t < t1; ++t) {
            uint4 cb = nb;
            int tn = (t + 1 < t1) ? t + 1 : t;
            nb = wpq[((size_t)tn * 4 + tile) * 64 + lane];
            bf16x8 af = __builtin_bit_cast(
                bf16x8, *(const uint4*)&Arows[l15 * NSTR2 + t * 36 + (q << 3)]);
            bf16x8 bfr = __builtin_bit_cast(bf16x8, cb);
            cacc = __builtin_amdgcn_mfma_f32_16x16x32_bf16(af, bfr, cacc, 0, 0, 0);
        }
        float* cpart = Cst + kq * (16 * 66);
#pragma unroll
        for (int r = 0; r < 4; ++r)
            cpart[(q * 4 + r) * 66 + tile * 16 + l15] = cacc[r];
    }
    __syncthreads();

    // ---- fused epilogue: reduce quarters + bias + relu -> bf16 h2 ----
    {
        int row = threadIdx.x >> 6;        // 0..15
        int col = threadIdx.x & 63;        // 0..63
        int idx = row * 66 + col;
        float v = Cst[idx] + Cst[16 * 66 + idx] + Cst[32 * 66 + idx] + Cst[48 * 66 + idx];
        v = fmaxf(v + b2[col], 0.0f);
        int n = blockIdx.x * 16 + row;
        h2bf[(size_t)n * 64 + col] = bf16_rne(v);
    }
}

// ---------------------------------------------------------------------------
// FUSED layer 3 (R18-proven layout): 1024 threads (16 waves), 16 nodes,
// 1 node/wave phase 1; Arows plain layout arow[kk*64+ch], ASTR=3160.
// Phase 2: 8 column tiles x 2-way K-split, reads Arows[l15*ASTR + t*32 + q*8].
// Fused reduce + bias + relu + log_softmax epilogue.
// LDS = 162,560 B -> 1 block/CU, 16 waves.
// ---------------------------------------------------------------------------
#define ASTR 3160
__global__ __launch_bounds__(1024) void fused_l3_kernel(
    const int* __restrict__ srcs, const unsigned short* __restrict__ bas8bf,
    const unsigned char* __restrict__ kidb, const int* __restrict__ row_start,
    const unsigned short* __restrict__ h2bf, const unsigned short* __restrict__ Wp3,
    const float* __restrict__ b3, float* __restrict__ out) {
    __shared__ unsigned short Arows[16 * ASTR];           // 101,120 B
    __shared__ unsigned short BtAll[16][KTOT * BTSTRIDE]; // 61,440 B (Cst overlay)
    float* Cst = (float*)&BtAll[0][0];                    // 2 x 16 x 130 fp32
    int w = threadIdx.x >> 6, lane = threadIdx.x & 63;
    int q = lane >> 4, l15 = lane & 15;
    unsigned short* Bt = &BtAll[w][0];

    // ---- phase 1: one node per wave (proven mfma_acc<64> body) ----
    {
        int n = blockIdx.x * 16 + w;
        int beg = row_start[n], end = row_start[n + 1];
        int cnt = end - beg;
        f32x4 acc[3][4] = {};
        for (int c0 = 0; c0 < cnt; c0 += 32) {
            uint4 z = make_uint4(0, 0, 0, 0);
            for (int l = lane; l < (KTOT * BTSTRIDE) / 8; l += 64) ((uint4*)Bt)[l] = z;
#pragma unroll
            for (int it = 0; it < 4; ++it) {
                int idx = it * 64 + lane;
                int jj = idx >> 3, s = idx & 7;
                int j = c0 + jj;
                if (j < cnt) {
                    unsigned short b = bas8bf[(size_t)(beg + j) * 8 + s];
                    int k = kidb[(size_t)(beg + j) * 8 + s];
                    Bt[k * BTSTRIDE + jj] = b;
                }
            }
            int srcv[8];
#pragma unroll
            for (int j = 0; j < 8; ++j) {
                int jc = c0 + q * 8 + j;
                jc = (jc < cnt) ? jc : (cnt - 1);
                srcv[j] = srcs[beg + jc];
            }
            bf16x8 afr[3];
#pragma unroll
            for (int mt = 0; mt < 3; ++mt) {
                uint4 raw = *(const uint4*)&Bt[(mt * 16 + l15) * BTSTRIDE + q * 8];
                afr[mt] = __builtin_bit_cast(bf16x8, raw);
            }
#pragma unroll
            for (int nt = 0; nt < 4; ++nt) {
                unsigned int bw[4];
#pragma unroll
                for (int jp = 0; jp < 4; ++jp) {
                    unsigned int lo = h2bf[(size_t)srcv[2 * jp] * 64 + nt * 16 + l15];
                    unsigned int hi = h2bf[(size_t)srcv[2 * jp + 1] * 64 + nt * 16 + l15];
                    bw[jp] = lo | (hi << 16);
                }
                uint4 braw = make_uint4(bw[0], bw[1], bw[2], bw[3]);
                bf16x8 bfr = __builtin_bit_cast(bf16x8, braw);
#pragma unroll
                for (int mt = 0; mt < 3; ++mt)
                    acc[mt][nt] = __builtin_amdgcn_mfma_f32_16x16x32_bf16(
                        afr[mt], bfr, acc[mt][nt], 0, 0, 0);
            }
        }
        unsigned short* arow = &Arows[w * ASTR];
#pragma unroll
        for (int mt = 0; mt < 3; ++mt)
#pragma unroll
            for (int nt = 0; nt < 4; ++nt)
#pragma unroll
                for (int r = 0; r < 4; ++r)
                    arow[(mt * 16 + q * 4 + r) * 64 + nt * 16 + l15] =
                        bf16_rne(acc[mt][nt][r]);
        arow[3072 + lane] = h2bf[(size_t)(blockIdx.x * 16 + w) * 64 + lane];
    }
    __syncthreads();

    // ---- phase 2: wave w -> column tile (w&7), K-half (w>>3) ----
    {
        int tile = w & 7;
        int half = w >> 3;
        int t0 = half * 49, t1 = t0 + 49;
        f32x4 cacc = {};
        const uint4* wpq = (const uint4*)Wp3;
        uint4 nb = wpq[((size_t)t0 * 8 + tile) * 64 + lane];
        for (int t = t0; t < t1; ++t) {
            uint4 cb = nb;
            int tn = (t + 1 < t1) ? t + 1 : t;
            nb = wpq[((size_t)tn * 8 + tile) * 64 + lane];
            bf16x8 af = __builtin_bit_cast(
                bf16x8, *(const uint4*)&Arows[l15 * ASTR + t * 32 + (q << 3)]);
            bf16x8 bfr = __builtin_bit_cast(bf16x8, cb);
            cacc = __builtin_amdgcn_mfma_f32_16x16x32_bf16(af, bfr, cacc, 0, 0, 0);
        }
        float* chalf = Cst + half * (16 * 130);
#pragma unroll
        for (int r = 0; r < 4; ++r)
            chalf[(q * 4 + r) * 130 + tile * 16 + l15] = cacc[r];
    }
    __syncthreads();

    // ---- fused epilogue: reduce halves + bias + relu + log_softmax ----
    if (threadIdx.x < 256) {
        int row = threadIdx.x >> 4;
        int cb0 = threadIdx.x & 15;
        float v[8];
        float mx = -1e30f;
#pragma unroll
        for (int c = 0; c < 8; ++c) {
            int idx = row * 130 + cb0 + c * 16;
            float s = Cst[idx] + Cst[16 * 130 + idx] + b3[cb0 + c * 16];
            s = fmaxf(s, 0.0f);
            v[c] = s;
            mx = fmaxf(mx, s);
        }
#pragma unroll
        for (int off = 8; off > 0; off >>= 1) mx = fmaxf(mx, __shfl_xor(mx, off));
        float se = 0.0f;
#pragma unroll
        for (int c = 0; c < 8; ++c) se += expf(v[c] - mx);
#pragma unroll
        for (int off = 8; off > 0; off >>= 1) se += __shfl_xor(se, off);
        float lse = mx + logf(se);
        int n = blockIdx.x * 16 + row;
#pragma unroll
        for (int c = 0; c < 8; ++c)
            out[(size_t)n * 128 + cb0 + c * 16] = v[c] - lse;
    }
}

// ---------------------------------------------------------------------------
// Launch
// ---------------------------------------------------------------------------
extern "C" void kernel_launch(void* const* d_in, const int* in_sizes, int n_in,
                              void* d_out, int out_size, void* d_ws, size_t ws_size,
                              hipStream_t stream) {
    const float* x = (const float*)d_in[0];
    const int* ei = (const int*)d_in[1];
    const float* pseudo = (const float*)d_in[2];
    const float* W1 = (const float*)d_in[3];
    const float* root1 = (const float*)d_in[4];
    const float* b1 = (const float*)d_in[5];
    const float* W2 = (const float*)d_in[6];
    const float* root2 = (const float*)d_in[7];
    const float* b2 = (const float*)d_in[8];
    const float* W3 = (const float*)d_in[9];
    const float* root3 = (const float*)d_in[10];
    const float* b3 = (const float*)d_in[11];
    float* out = (float*)d_out;
    char* ws = (char*)d_ws;

    const int N = NN_NODES, E = NE_EDGES;
    const int Kp2 = 49 * 32;   // 1568
    const int Kp3 = 49 * 64;   // 3136
    size_t off = 0;
    auto carve = [&](size_t bytes) {
        size_t p = off;
        off += (bytes + 255) & ~(size_t)255;
        return p;
    };
    int* counts = (int*)(ws + carve((size_t)N * 4 * 2));
    int* cursor = counts + N;
    int* row_start = (int*)(ws + carve((size_t)(N + 1) * 4));
    int* srcs = (int*)(ws + carve((size_t)E * 4));
    unsigned short* bas8bf = (unsigned short*)(ws + carve((size_t)E * 8 * 2));
    unsigned char* kidb = (unsigned char*)(ws + carve((size_t)E * 8));
    unsigned short* h1bf = (unsigned short*)(ws + carve((size_t)N * 32 * 2));
    unsigned short* h2bf = (unsigned short*)(ws + carve((size_t)N * 64 * 2));
    unsigned short* Wp2 = (unsigned short*)(ws + carve((size_t)Kp2 * 64 * 2));
    unsigned short* Wp3 = (unsigned short*)(ws + carve((size_t)Kp3 * 128 * 2));

    int egrid = (E + 255) / 256;

    // CSR + sorted edge metadata (fill fused into edge_prep)
    zero_kernel<<<(2 * N + 255) / 256, 256, 0, stream>>>(counts, 2 * N);
    count_kernel<<<egrid, 256, 0, stream>>>(ei, counts);
    scan_kernel<<<1, 256, 0, stream>>>(counts, row_start);
    edge_prep_sorted<<<egrid, 256, 0, stream>>>(pseudo, ei, row_start, cursor,
                                                srcs, bas8bf, kidb);

    // pack weights (bf16 MFMA B-fragment order)
    int tot2 = (Kp2 / 32) * (64 / 16) * 64;
    int tot3 = (Kp3 / 32) * (128 / 16) * 64;
    pack_w_kernel<<<(tot2 + 255) / 256, 256, 0, stream>>>(W2, root2, KTOT * 32, 64, tot2, Wp2);
    pack_w_kernel<<<(tot3 + 255) / 256, 256, 0, stream>>>(W3, root3, KTOT * 64, 128, tot3, Wp3);

    // layer 1 (fused accumulate + dense + relu) -> bf16 h1
    layer1_fused_kernel<<<(N + 3) / 4, 256, 0, stream>>>(srcs, bas8bf, kidb, row_start, x,
                                                         W1, root1, b1, h1bf);

    // layer 2: single fused kernel (acc + GEMM + bias/relu) -> bf16 h2
    fused_l2_kernel<<<N / 16, 1024, 0, stream>>>(srcs, bas8bf, kidb, row_start,
                                                 h1bf, Wp2, b2, h2bf);

    // layer 3: single fused kernel (acc + GEMM + epilogue) -> out
    fused_l3_kernel<<<N / 16, 1024, 0, stream>>>(srcs, bas8bf, kidb, row_start,
                                                 h2bf, Wp3, b3, out);
}